// Round 13
// baseline (102.578 us; speedup 1.0000x reference)
//
#include <hip/hip_runtime.h>
#include <hip/hip_bf16.h>

#define K_DIM 16384
#define M_DIM 512
#define N_DIM 2560
#define BM 128
#define BN 128
#define BK 64
#define KSPLIT 8
#define KCH (K_DIM / KSPLIT)   // 2048
#define NT (KCH / BK)          // 32

typedef float f32x4 __attribute__((ext_vector_type(4)));
typedef __bf16 bf16x8 __attribute__((ext_vector_type(8)));

__device__ __forceinline__ unsigned short f2bf(float f){
  union { float f; unsigned u; } v; v.f = f;
  unsigned r = v.u + 0x7FFFu + ((v.u >> 16) & 1u);
  return (unsigned short)(r >> 16);
}
__device__ __forceinline__ unsigned bfpack2(float lo, float hi){
  return (unsigned)f2bf(lo) | ((unsigned)f2bf(hi) << 16);
}
// compiler-cvt pack (emits v_cvt_pk_bf16_f32) for the GEMM hot path
__device__ __forceinline__ unsigned cpk2(float lo, float hi){
  __bf16 a = (__bf16)lo, b = (__bf16)hi;
  unsigned short ua = __builtin_bit_cast(unsigned short, a);
  unsigned short ub = __builtin_bit_cast(unsigned short, b);
  return (unsigned)ua | ((unsigned)ub << 16);
}

// K1: w_mean[c] = mean_f conv1_w[f][c]; b_mean = mean(conv1_b)
__global__ __launch_bounds__(256)
void prep_kernel(const float* __restrict__ conv1_w, const float* __restrict__ conv1_b,
                 float* __restrict__ w_mean, float* __restrict__ b_mean)
{
  int c = blockIdx.x * 256 + threadIdx.x;
  if (c < K_DIM){
    float s = 0.f;
    #pragma unroll
    for (int f = 0; f < 10; ++f) s += conv1_w[f * K_DIM + c];
    w_mean[c] = s * 0.1f;
  }
  if (blockIdx.x == 0 && threadIdx.x == 0){
    float s = 0.f;
    #pragma unroll
    for (int f = 0; f < 10; ++f) s += conv1_b[f];
    *b_mean = s * 0.1f;
  }
}

// K2: pooled[row] = x[row,:].w_mean + b_mean  AND  xbf[row,:] = bf16(x[row,:])
__global__ __launch_bounds__(256)
void pooled_kernel(const float* __restrict__ X, const float* __restrict__ w_mean,
                   const float* __restrict__ b_mean, float* __restrict__ pooled,
                   unsigned short* __restrict__ xbf)
{
  const int row = blockIdx.x;
  const int tid = threadIdx.x;
  const float* xr = X + (size_t)row * K_DIM;
  unsigned short* xb = xbf + (size_t)row * K_DIM;
  float s = 0.f;
  #pragma unroll 2
  for (int i = 0; i < 8; ++i){
    int idx = (tid + 256 * i) * 8;
    float4 a0 = *(const float4*)(xr + idx);
    float4 a1 = *(const float4*)(xr + idx + 4);
    float4 w0 = *(const float4*)(w_mean + idx);
    float4 w1 = *(const float4*)(w_mean + idx + 4);
    s += a0.x*w0.x + a0.y*w0.y + a0.z*w0.z + a0.w*w0.w
       + a1.x*w1.x + a1.y*w1.y + a1.z*w1.z + a1.w*w1.w;
    uint4 p;
    p.x = bfpack2(a0.x, a0.y); p.y = bfpack2(a0.z, a0.w);
    p.z = bfpack2(a1.x, a1.y); p.w = bfpack2(a1.z, a1.w);
    *(uint4*)(xb + idx) = p;
  }
  #pragma unroll
  for (int off = 32; off; off >>= 1) s += __shfl_down(s, off);
  __shared__ float red[4];
  if ((tid & 63) == 0) red[tid >> 6] = s;
  __syncthreads();
  if (tid == 0) pooled[row] = red[0] + red[1] + red[2] + red[3] + *b_mean;
}

// K3: gates
__global__ __launch_bounds__(512)
void gates_kernel(const float* __restrict__ pooled, const float* __restrict__ fw,
                  const float* __restrict__ fb, const float* __restrict__ aw,
                  float* __restrict__ gates)
{
  __shared__ float ps[512];
  int tid = threadIdx.x;
  ps[tid] = pooled[tid];
  __syncthreads();
  int b = tid >> 5, s = tid & 31;
  float z = fb[s];
  #pragma unroll
  for (int t = 0; t < 32; ++t) z += ps[b * 32 + t] * fw[s * 32 + t];
  float mx = z;
  #pragma unroll
  for (int off = 16; off; off >>= 1) mx = fmaxf(mx, __shfl_xor(mx, off));
  float e = expf(z - mx);
  float sum = e;
  #pragma unroll
  for (int off = 16; off; off >>= 1) sum += __shfl_xor(sum, off);
  float sm = e / sum;
  float relu = z > 0.f ? z : 0.f;
  float sig = 1.f / (1.f + expf(-z));
  gates[tid] = aw[0] * relu + aw[1] * sig + aw[2] * sm;
}

// K4 v12: m97-replica geometry for CO-RESIDENCY overlap (m114 mechanism).
// BM=BN=128, BK=64, 4 waves (256 thr), wave tile 64x64 (acc[4][4]).
// LDS 32KB: A 16KB + B 16KB, SINGLE-buffered, plain __syncthreads 2-barrier loop
// -- each block's stage/drain stall is covered by the other 2 resident blocks.
// launch_bounds(256,3): VGPR<=170 -> 3 waves/SIMD -> up to 3 blocks/CU.
// Grid 4*20*8 = 640 (2.5 blocks/CU). kz=id&7 XCD-pinned; m-fastest so the 4
// m-blocks sharing a W-strip run on one XCD (3 of 4 W reads hit L2).
// A: gll w/ pre-swizzled source (bf16 from xbf). B: fp32 1-deep reg prefetch,
// compiler cvt_pk -> bf16, ds_write (fused conversion; W read exactly once).
__global__ __launch_bounds__(256, 3)
void gemm_kernel(const unsigned short* __restrict__ Abf, const float* __restrict__ W,
                 float* __restrict__ outp, int mode)
{
  __shared__ __align__(16) char smem[32768];   // A 16KB | B 16KB
  char* As = smem;
  char* Bs = smem + 16384;

  const int tid  = threadIdx.x;
  const int lane = tid & 63;
  const int wv   = tid >> 6;           // 0..3
  const int wm   = (wv >> 1) * 64;
  const int wn   = (wv & 1) * 64;

  const int id = blockIdx.x;
  const int kz = id & 7;
  const int r  = id >> 3;              // 0..79
  const int m0 = (r & 3) * BM;         // m-fastest: W-strip sharers same XCD
  const int n0 = (r >> 2) * BN;
  const int kbase = kz * KCH;

  f32x4 acc[4][4] = {};

  // A gll: chunk u = j*256 + tid -> row = j*32 + (tid>>3), c8 = tid&7.
  // LDS[row][c8] holds A[row][c8 ^ (row&7)]; row&7 == (tid>>3)&7.
  const int arow0 = tid >> 3;          // 0..31
  const int ac8   = (tid & 7) ^ (arow0 & 7);
  const unsigned short* asrc = Abf + (size_t)(m0 + arow0) * K_DIM + ac8 * 8;
  const int adst = tid * 16;

  auto stageA = [&](int k0){
    #pragma unroll
    for (int j = 0; j < 4; ++j){
      __builtin_amdgcn_global_load_lds(
        (const __attribute__((address_space(1))) void*)(asrc + (size_t)j * 32 * K_DIM + k0),
        (__attribute__((address_space(3))) void*)(As + j * 4096 + adst),
        16, 0, 0);
    }
  };

  // B: 128 rows x 16 float4 chunks = 2048; thread handles u = j*256+tid, j=0..7
  const int btrow = tid >> 4;          // 0..15
  const int bc4   = tid & 15;
  const float* bsrc = W + (size_t)(n0 + btrow) * K_DIM + kbase + bc4 * 4;
  const int boff = btrow * 128 + ((bc4 * 8) ^ ((btrow & 7) << 4));

  auto loadB = [&](int kt, float4* rr){
    #pragma unroll
    for (int j = 0; j < 8; ++j)
      rr[j] = *(const float4*)(bsrc + (size_t)j * 16 * K_DIM + kt * BK);
  };
  auto writeB = [&](const float4* rr){
    #pragma unroll
    for (int j = 0; j < 8; ++j){
      uint2 u;
      u.x = cpk2(rr[j].x, rr[j].y);
      u.y = cpk2(rr[j].z, rr[j].w);
      *(uint2*)(Bs + j * 2048 + boff) = u;
    }
  };

  auto compute = [&](){
    #pragma unroll
    for (int kk = 0; kk < 2; ++kk){
      bf16x8 af[4], bfv[4];
      const int kbyte = kk * 64 + (lane >> 4) * 16;
      #pragma unroll
      for (int i = 0; i < 4; ++i){
        int row = wm + i * 16 + (lane & 15);
        af[i] = *(const bf16x8*)(As + row * 128 + (kbyte ^ ((row & 7) << 4)));
      }
      #pragma unroll
      for (int j = 0; j < 4; ++j){
        int rowb = wn + j * 16 + (lane & 15);
        bfv[j] = *(const bf16x8*)(Bs + rowb * 128 + (kbyte ^ ((rowb & 7) << 4)));
      }
      #pragma unroll
      for (int i = 0; i < 4; ++i)
        #pragma unroll
        for (int j = 0; j < 4; ++j)
          acc[i][j] = __builtin_amdgcn_mfma_f32_16x16x32_bf16(af[i], bfv[j], acc[i][j], 0, 0, 0);
    }
  };

  float4 rb[8];
  // prologue: stage tile 0 (A gll + B load/cvt/write), prefetch B(1) regs
  stageA(kbase);
  loadB(0, rb);
  writeB(rb);
  loadB(1, rb);
  __syncthreads();                 // tile 0 published (vmcnt+lgkm drained)

  for (int t = 0; t < NT; ++t){
    compute();
    __syncthreads();               // all waves done reading tile t
    if (t + 1 < NT){
      stageA(kbase + (t + 1) * BK);      // gll into As
      writeB(rb);                        // cvt + ds_write B(t+1)
      if (t + 2 < NT) loadB(t + 2, rb);  // prefetch next B regs
    }
    __syncthreads();               // publish tile t+1 (drains gll + ds_write)
  }

  if (mode == 0){
    float* P = outp + (size_t)kz * M_DIM * N_DIM;
    #pragma unroll
    for (int i = 0; i < 4; ++i){
      int rbase = m0 + wm + i * 16 + (lane >> 4) * 4;
      #pragma unroll
      for (int j = 0; j < 4; ++j){
        int col = n0 + wn + j * 16 + (lane & 15);
        #pragma unroll
        for (int r2 = 0; r2 < 4; ++r2)
          P[(size_t)(rbase + r2) * N_DIM + col] = acc[i][j][r2];
      }
    }
  } else {
    #pragma unroll
    for (int i = 0; i < 4; ++i){
      int rbase = m0 + wm + i * 16 + (lane >> 4) * 4;
      #pragma unroll
      for (int j = 0; j < 4; ++j){
        int col = n0 + wn + j * 16 + (lane & 15);
        #pragma unroll
        for (int r2 = 0; r2 < 4; ++r2)
          atomicAdd(&outp[(size_t)(rbase + r2) * N_DIM + col], acc[i][j][r2]);
      }
    }
  }
}

// K5a: out[m,n] = gates[m] * (sum_z partial[z,m,n] + bias[n])
__global__ __launch_bounds__(256)
void reduce_kernel(const float* __restrict__ part, const float* __restrict__ gates,
                   const float* __restrict__ bias, float* __restrict__ out, int ksplit)
{
  int i4 = blockIdx.x * 256 + threadIdx.x;
  if (i4 >= M_DIM * N_DIM / 4) return;
  size_t off = (size_t)i4 * 4;
  int m = (int)(off / N_DIM);
  int n = (int)(off % N_DIM);
  float sx = 0.f, sy = 0.f, sz = 0.f, sw = 0.f;
  for (int z = 0; z < ksplit; ++z){
    float4 p = *(const float4*)(part + (size_t)z * M_DIM * N_DIM + off);
    sx += p.x; sy += p.y; sz += p.z; sw += p.w;
  }
  float4 bv = *(const float4*)(bias + n);
  float g = gates[m];
  float4 o;
  o.x = g * (sx + bv.x); o.y = g * (sy + bv.y);
  o.z = g * (sz + bv.z); o.w = g * (sw + bv.w);
  *(float4*)(out + off) = o;
}

// K5b: finalize after atomic accumulation
__global__ __launch_bounds__(256)
void finalize_kernel(float* __restrict__ out, const float* __restrict__ gates,
                     const float* __restrict__ bias)
{
  int i4 = blockIdx.x * 256 + threadIdx.x;
  if (i4 >= M_DIM * N_DIM / 4) return;
  size_t off = (size_t)i4 * 4;
  int m = (int)(off / N_DIM);
  int n = (int)(off % N_DIM);
  float4 o = *(const float4*)(out + off);
  float4 bv = *(const float4*)(bias + n);
  float g = gates[m];
  o.x = g * (o.x + bv.x); o.y = g * (o.y + bv.y);
  o.z = g * (o.z + bv.z); o.w = g * (o.w + bv.w);
  *(float4*)(out + off) = o;
}

extern "C" void kernel_launch(void* const* d_in, const int* in_sizes, int n_in,
                              void* d_out, int out_size, void* d_ws, size_t ws_size,
                              hipStream_t stream)
{
  const float* input   = (const float*)d_in[0];
  const float* aw      = (const float*)d_in[2];
  const float* conv1_w = (const float*)d_in[3];
  const float* conv1_b = (const float*)d_in[4];
  const float* G3_w    = (const float*)d_in[5];
  const float* G3_b    = (const float*)d_in[6];
  const float* ffnn1_w = (const float*)d_in[7];
  const float* ffnn1_b = (const float*)d_in[8];
  float* out = (float*)d_out;

  float* wsf    = (float*)d_ws;
  float* w_mean = wsf;               // 16384 f
  float* pooled = wsf + 16384;       // 512 f
  float* gates  = wsf + 16896;       // 512 f
  float* b_mean = wsf + 17408;       // 64 f pad
  unsigned short* xbf = (unsigned short*)(wsf + 17472);        // 16 MB
  float* partial = wsf + 17472 + (size_t)M_DIM * K_DIM / 2;    // 8 * 512*2560 f

  const size_t need_det = ((size_t)17472 + (size_t)M_DIM * K_DIM / 2
                           + (size_t)KSPLIT * M_DIM * N_DIM) * 4;   // ~58.8MB

  prep_kernel<<<64, 256, 0, stream>>>(conv1_w, conv1_b, w_mean, b_mean);
  pooled_kernel<<<512, 256, 0, stream>>>(input, w_mean, b_mean, pooled, xbf);
  gates_kernel<<<1, 512, 0, stream>>>(pooled, ffnn1_w, ffnn1_b, aw, gates);

  const int n4 = M_DIM * N_DIM / 4;
  const int grid = (M_DIM / BM) * (N_DIM / BN) * KSPLIT;   // 4*20*8 = 640
  if (ws_size >= need_det){
    gemm_kernel<<<grid, 256, 0, stream>>>(xbf, G3_w, partial, 0);
    reduce_kernel<<<(n4 + 255) / 256, 256, 0, stream>>>(partial, gates, G3_b, out, KSPLIT);
  } else {
    hipMemsetAsync(d_out, 0, (size_t)out_size * sizeof(float), stream);
    gemm_kernel<<<grid, 256, 0, stream>>>(xbf, G3_w, out, 2);
    finalize_kernel<<<(n4 + 255) / 256, 256, 0, stream>>>(out, gates, G3_b);
  }
}

// Round 14
// 100.998 us; speedup vs baseline: 1.0156x; 1.0156x over previous
//
#include <hip/hip_runtime.h>
#include <hip/hip_bf16.h>

#define K_DIM 16384
#define M_DIM 512
#define N_DIM 2560
#define BM 128
#define BN 160
#define BK 64
#define KSPLIT 8
#define KCH (K_DIM / KSPLIT)   // 2048
#define NT (KCH / BK)          // 32

typedef float f32x4 __attribute__((ext_vector_type(4)));
typedef __bf16 bf16x8 __attribute__((ext_vector_type(8)));

__device__ __forceinline__ unsigned short f2bf(float f){
  union { float f; unsigned u; } v; v.f = f;
  unsigned r = v.u + 0x7FFFu + ((v.u >> 16) & 1u);
  return (unsigned short)(r >> 16);
}
__device__ __forceinline__ unsigned bfpack2(float lo, float hi){
  return (unsigned)f2bf(lo) | ((unsigned)f2bf(hi) << 16);
}
// compiler-cvt pack (emits v_cvt_pk_bf16_f32)
__device__ __forceinline__ unsigned cpk2(float lo, float hi){
  __bf16 a = (__bf16)lo, b = (__bf16)hi;
  unsigned short ua = __builtin_bit_cast(unsigned short, a);
  unsigned short ub = __builtin_bit_cast(unsigned short, b);
  return (unsigned)ua | ((unsigned)ub << 16);
}

// K1: w_mean[c] = mean_f conv1_w[f][c]; b_mean = mean(conv1_b)
__global__ __launch_bounds__(256)
void prep_kernel(const float* __restrict__ conv1_w, const float* __restrict__ conv1_b,
                 float* __restrict__ w_mean, float* __restrict__ b_mean)
{
  int c = blockIdx.x * 256 + threadIdx.x;
  if (c < K_DIM){
    float s = 0.f;
    #pragma unroll
    for (int f = 0; f < 10; ++f) s += conv1_w[f * K_DIM + c];
    w_mean[c] = s * 0.1f;
  }
  if (blockIdx.x == 0 && threadIdx.x == 0){
    float s = 0.f;
    #pragma unroll
    for (int f = 0; f < 10; ++f) s += conv1_b[f];
    *b_mean = s * 0.1f;
  }
}

// K2: pooled[row] = x[row,:].w_mean + b_mean  AND  xbf[row,:] = bf16(x[row,:])
__global__ __launch_bounds__(256)
void pooled_kernel(const float* __restrict__ X, const float* __restrict__ w_mean,
                   const float* __restrict__ b_mean, float* __restrict__ pooled,
                   unsigned short* __restrict__ xbf)
{
  const int row = blockIdx.x;
  const int tid = threadIdx.x;
  const float* xr = X + (size_t)row * K_DIM;
  unsigned short* xb = xbf + (size_t)row * K_DIM;
  float s = 0.f;
  #pragma unroll 2
  for (int i = 0; i < 8; ++i){
    int idx = (tid + 256 * i) * 8;
    float4 a0 = *(const float4*)(xr + idx);
    float4 a1 = *(const float4*)(xr + idx + 4);
    float4 w0 = *(const float4*)(w_mean + idx);
    float4 w1 = *(const float4*)(w_mean + idx + 4);
    s += a0.x*w0.x + a0.y*w0.y + a0.z*w0.z + a0.w*w0.w
       + a1.x*w1.x + a1.y*w1.y + a1.z*w1.z + a1.w*w1.w;
    uint4 p;
    p.x = bfpack2(a0.x, a0.y); p.y = bfpack2(a0.z, a0.w);
    p.z = bfpack2(a1.x, a1.y); p.w = bfpack2(a1.z, a1.w);
    *(uint4*)(xb + idx) = p;
  }
  #pragma unroll
  for (int off = 32; off; off >>= 1) s += __shfl_down(s, off);
  __shared__ float red[4];
  if ((tid & 63) == 0) red[tid >> 6] = s;
  __syncthreads();
  if (tid == 0) pooled[row] = red[0] + red[1] + red[2] + red[3] + *b_mean;
}

// K3: gates
__global__ __launch_bounds__(512)
void gates_kernel(const float* __restrict__ pooled, const float* __restrict__ fw,
                  const float* __restrict__ fb, const float* __restrict__ aw,
                  float* __restrict__ gates)
{
  __shared__ float ps[512];
  int tid = threadIdx.x;
  ps[tid] = pooled[tid];
  __syncthreads();
  int b = tid >> 5, s = tid & 31;
  float z = fb[s];
  #pragma unroll
  for (int t = 0; t < 32; ++t) z += ps[b * 32 + t] * fw[s * 32 + t];
  float mx = z;
  #pragma unroll
  for (int off = 16; off; off >>= 1) mx = fmaxf(mx, __shfl_xor(mx, off));
  float e = expf(z - mx);
  float sum = e;
  #pragma unroll
  for (int off = 16; off; off >>= 1) sum += __shfl_xor(sum, off);
  float sm = e / sum;
  float relu = z > 0.f ? z : 0.f;
  float sig = 1.f / (1.f + expf(-z));
  gates[tid] = aw[0] * relu + aw[1] * sig + aw[2] * sm;
}

// K4 v13: counted-vmcnt single-barrier pipeline (T4 done RIGHT).
// BM=128 x BN=160, BK=64, KSPLIT=8 -> grid 512 (exactly 2 blocks/CU @ 72KB LDS).
// 4 waves, wave tile 64x80 (acc[4][5]). A,B double-buffered.
// Per K-step (ONE barrier): writeB(t+1) [rb loads 1 step old: compiler vmcnt(4)
// keeps newer gll]; issue loadB(t+2) [rides across barrier]; compute(t) [covers
// gll(t+1)]; vmcnt(10) [drains exactly gll(t+1), keeps B(t+2)]; s_barrier;
// issue gll A(t+2) into the A-buffer just freed. No fresh load is ever drained.
__global__ __launch_bounds__(256, 2)
void gemm_kernel(const unsigned short* __restrict__ Abf, const float* __restrict__ W,
                 float* __restrict__ outp, int mode)
{
  __shared__ __align__(16) char smem[73728];   // A[2] 16KB | B[2] 20KB

  const int tid  = threadIdx.x;
  const int lane = tid & 63;
  const int wv   = tid >> 6;            // 0..3
  const int wm   = (wv >> 1) * 64;      // 2 m-waves
  const int wn   = (wv & 1) * 80;       // 2 n-waves

  const int id = blockIdx.x;
  const int kz = id & 7;
  const int r  = id >> 3;               // 0..63
  const int m0 = (r & 3) * BM;          // m-fastest: W-strip sharers same XCD
  const int n0 = (r >> 2) * BN;
  const int kbase = kz * KCH;

  f32x4 acc[4][5] = {};

  // A gll: chunk u = j*256 + tid -> row = j*32 + (tid>>3), c8 = tid&7.
  // LDS[row][c8] holds A[row][c8 ^ (row&7)]; row&7 == (tid>>3)&7.
  const int arow0 = tid >> 3;
  const int ac8   = (tid & 7) ^ (arow0 & 7);
  const unsigned short* asrc = Abf + (size_t)(m0 + arow0) * K_DIM + ac8 * 8;
  const int adst = tid * 16;

  auto stageA = [&](char* dst, int k0){
    #pragma unroll
    for (int j = 0; j < 4; ++j){
      __builtin_amdgcn_global_load_lds(
        (const __attribute__((address_space(1))) void*)(asrc + (size_t)j * 32 * K_DIM + k0),
        (__attribute__((address_space(3))) void*)(dst + j * 4096 + adst),
        16, 0, 0);
    }
  };

  // B: 160 rows x 16 float4 = 2560 chunks; thread u = j*256+tid (j=0..9)
  //   brow = j*16 + (tid>>4), bc4 = tid&15; brow&7 j-invariant.
  const int btrow = tid >> 4;           // 0..15
  const int bc4   = tid & 15;
  const float* bsrc = W + (size_t)(n0 + btrow) * K_DIM + kbase + bc4 * 4;
  const int boff0 = btrow * 128 + ((bc4 * 8) ^ ((btrow & 7) << 4));

  float4 rb[10];
  auto loadB = [&](int kt){
    #pragma unroll
    for (int j = 0; j < 10; ++j)
      rb[j] = *(const float4*)(bsrc + (size_t)j * 16 * K_DIM + kt * BK);
  };
  auto writeB = [&](char* dst){
    #pragma unroll
    for (int j = 0; j < 10; ++j){
      uint2 u;
      u.x = cpk2(rb[j].x, rb[j].y);
      u.y = cpk2(rb[j].z, rb[j].w);
      *(uint2*)(dst + j * 2048 + boff0) = u;
    }
  };

  auto compute = [&](const char* A_, const char* B_){
    #pragma unroll
    for (int kk = 0; kk < 2; ++kk){
      bf16x8 af[4], bfv[5];
      const int kbyte = kk * 64 + (lane >> 4) * 16;
      #pragma unroll
      for (int i = 0; i < 4; ++i){
        int row = wm + i * 16 + (lane & 15);
        af[i] = *(const bf16x8*)(A_ + row * 128 + (kbyte ^ ((row & 7) << 4)));
      }
      #pragma unroll
      for (int j = 0; j < 5; ++j){
        int rowb = wn + j * 16 + (lane & 15);
        bfv[j] = *(const bf16x8*)(B_ + rowb * 128 + (kbyte ^ ((rowb & 7) << 4)));
      }
      #pragma unroll
      for (int i = 0; i < 4; ++i)
        #pragma unroll
        for (int j = 0; j < 5; ++j)
          acc[i][j] = __builtin_amdgcn_mfma_f32_16x16x32_bf16(af[i], bfv[j], acc[i][j], 0, 0, 0);
    }
  };

  // ---- prologue ----
  // order matters for the vmcnt ledger: B0(10) oldest, then gll0(4), ...
  loadB(0);                                   // 10 vm
  stageA(smem, kbase);                        // +4 (gll0)
  writeB(smem + 32768);                       // rb use -> compiler vmcnt(4): B0 done, gll0 flies
  loadB(1);                                   // +10
  stageA(smem + 16384, kbase + BK);           // +4 (gll1)
  asm volatile("s_waitcnt vmcnt(14) lgkmcnt(0)" ::: "memory");  // drain gll0 + B0 ds_writes
  __builtin_amdgcn_s_barrier();               // tile0 published; B1+gll1 in flight
  __builtin_amdgcn_sched_barrier(0);

  // ---- main loop: ONE barrier per K-step ----
  for (int t = 0; t < NT; ++t){
    char* Ac = smem + ((t & 1) << 14);
    char* Bc = smem + 32768 + (t & 1) * 20480;
    char* Bn = smem + 32768 + ((t + 1) & 1) * 20480;
    writeB(Bn);                               // B(t+1)->LDS; rb wait keeps newer gll
    loadB(t + 2 < NT ? t + 2 : NT - 1);       // 10 vm ride across the barrier
    compute(Ac, Bc);                          // covers gll(t+1) latency
    asm volatile("s_waitcnt vmcnt(10) lgkmcnt(0)" ::: "memory");  // drain gll(t+1) only
    __builtin_amdgcn_s_barrier();             // publish tile t+1
    __builtin_amdgcn_sched_barrier(0);
    if (t + 2 < NT)
      stageA(Ac, kbase + (t + 2) * BK);       // gll A(t+2) into freed buffer
  }

  // ---- epilogue ----
  if (mode == 0){
    float* P = outp + (size_t)kz * M_DIM * N_DIM;
    #pragma unroll
    for (int i = 0; i < 4; ++i){
      int rbase = m0 + wm + i * 16 + (lane >> 4) * 4;
      #pragma unroll
      for (int j = 0; j < 5; ++j){
        int col = n0 + wn + j * 16 + (lane & 15);
        #pragma unroll
        for (int r2 = 0; r2 < 4; ++r2)
          P[(size_t)(rbase + r2) * N_DIM + col] = acc[i][j][r2];
      }
    }
  } else {
    #pragma unroll
    for (int i = 0; i < 4; ++i){
      int rbase = m0 + wm + i * 16 + (lane >> 4) * 4;
      #pragma unroll
      for (int j = 0; j < 5; ++j){
        int col = n0 + wn + j * 16 + (lane & 15);
        #pragma unroll
        for (int r2 = 0; r2 < 4; ++r2)
          atomicAdd(&outp[(size_t)(rbase + r2) * N_DIM + col], acc[i][j][r2]);
      }
    }
  }
}

// K5a: out[m,n] = gates[m] * (sum_z partial[z,m,n] + bias[n])
__global__ __launch_bounds__(256)
void reduce_kernel(const float* __restrict__ part, const float* __restrict__ gates,
                   const float* __restrict__ bias, float* __restrict__ out, int ksplit)
{
  int i4 = blockIdx.x * 256 + threadIdx.x;
  if (i4 >= M_DIM * N_DIM / 4) return;
  size_t off = (size_t)i4 * 4;
  int m = (int)(off / N_DIM);
  int n = (int)(off % N_DIM);
  float sx = 0.f, sy = 0.f, sz = 0.f, sw = 0.f;
  for (int z = 0; z < ksplit; ++z){
    float4 p = *(const float4*)(part + (size_t)z * M_DIM * N_DIM + off);
    sx += p.x; sy += p.y; sz += p.z; sw += p.w;
  }
  float4 bv = *(const float4*)(bias + n);
  float g = gates[m];
  float4 o;
  o.x = g * (sx + bv.x); o.y = g * (sy + bv.y);
  o.z = g * (sz + bv.z); o.w = g * (sw + bv.w);
  *(float4*)(out + off) = o;
}

// K5b: finalize after atomic accumulation
__global__ __launch_bounds__(256)
void finalize_kernel(float* __restrict__ out, const float* __restrict__ gates,
                     const float* __restrict__ bias)
{
  int i4 = blockIdx.x * 256 + threadIdx.x;
  if (i4 >= M_DIM * N_DIM / 4) return;
  size_t off = (size_t)i4 * 4;
  int m = (int)(off / N_DIM);
  int n = (int)(off % N_DIM);
  float4 o = *(const float4*)(out + off);
  float4 bv = *(const float4*)(bias + n);
  float g = gates[m];
  o.x = g * (o.x + bv.x); o.y = g * (o.y + bv.y);
  o.z = g * (o.z + bv.z); o.w = g * (o.w + bv.w);
  *(float4*)(out + off) = o;
}

extern "C" void kernel_launch(void* const* d_in, const int* in_sizes, int n_in,
                              void* d_out, int out_size, void* d_ws, size_t ws_size,
                              hipStream_t stream)
{
  const float* input   = (const float*)d_in[0];
  const float* aw      = (const float*)d_in[2];
  const float* conv1_w = (const float*)d_in[3];
  const float* conv1_b = (const float*)d_in[4];
  const float* G3_w    = (const float*)d_in[5];
  const float* G3_b    = (const float*)d_in[6];
  const float* ffnn1_w = (const float*)d_in[7];
  const float* ffnn1_b = (const float*)d_in[8];
  float* out = (float*)d_out;

  float* wsf    = (float*)d_ws;
  float* w_mean = wsf;               // 16384 f
  float* pooled = wsf + 16384;       // 512 f
  float* gates  = wsf + 16896;       // 512 f
  float* b_mean = wsf + 17408;       // 64 f pad
  unsigned short* xbf = (unsigned short*)(wsf + 17472);        // 16 MB
  float* partial = wsf + 17472 + (size_t)M_DIM * K_DIM / 2;    // 8 * 512*2560 f

  const size_t need_det = ((size_t)17472 + (size_t)M_DIM * K_DIM / 2
                           + (size_t)KSPLIT * M_DIM * N_DIM) * 4;   // ~58.8MB

  prep_kernel<<<64, 256, 0, stream>>>(conv1_w, conv1_b, w_mean, b_mean);
  pooled_kernel<<<512, 256, 0, stream>>>(input, w_mean, b_mean, pooled, xbf);
  gates_kernel<<<1, 512, 0, stream>>>(pooled, ffnn1_w, ffnn1_b, aw, gates);

  const int n4 = M_DIM * N_DIM / 4;
  const int grid = (M_DIM / BM) * (N_DIM / BN) * KSPLIT;   // 4*16*8 = 512
  if (ws_size >= need_det){
    gemm_kernel<<<grid, 256, 0, stream>>>(xbf, G3_w, partial, 0);
    reduce_kernel<<<(n4 + 255) / 256, 256, 0, stream>>>(partial, gates, G3_b, out, KSPLIT);
  } else {
    hipMemsetAsync(d_out, 0, (size_t)out_size * sizeof(float), stream);
    gemm_kernel<<<grid, 256, 0, stream>>>(xbf, G3_w, out, 2);
    finalize_kernel<<<(n4 + 255) / 256, 256, 0, stream>>>(out, gates, G3_b);
  }
}

// Round 16
// 88.122 us; speedup vs baseline: 1.1641x; 1.1461x over previous
//
#include <hip/hip_runtime.h>
#include <hip/hip_bf16.h>

#define K_DIM 16384
#define M_DIM 512
#define N_DIM 2560
#define BM 256
#define BN 160
#define BK 64
#define KSPLIT 8
#define KCH (K_DIM / KSPLIT)   // 2048
#define NT (KCH / BK)          // 32

typedef float f32x4 __attribute__((ext_vector_type(4)));
typedef __bf16 bf16x8 __attribute__((ext_vector_type(8)));

__device__ __forceinline__ unsigned short f2bf(float f){
  union { float f; unsigned u; } v; v.f = f;
  unsigned r = v.u + 0x7FFFu + ((v.u >> 16) & 1u);
  return (unsigned short)(r >> 16);
}
__device__ __forceinline__ unsigned bfpack2(float lo, float hi){
  return (unsigned)f2bf(lo) | ((unsigned)f2bf(hi) << 16);
}
// compiler-cvt pack (emits v_cvt_pk_bf16_f32)
__device__ __forceinline__ unsigned cpk2(float lo, float hi){
  __bf16 a = (__bf16)lo, b = (__bf16)hi;
  unsigned short ua = __builtin_bit_cast(unsigned short, a);
  unsigned short ub = __builtin_bit_cast(unsigned short, b);
  return (unsigned)ua | ((unsigned)ub << 16);
}

// K1: w_mean[c] = mean_f conv1_w[f][c]; b_mean = mean(conv1_b)
__global__ __launch_bounds__(256)
void prep_kernel(const float* __restrict__ conv1_w, const float* __restrict__ conv1_b,
                 float* __restrict__ w_mean, float* __restrict__ b_mean)
{
  int c = blockIdx.x * 256 + threadIdx.x;
  if (c < K_DIM){
    float s = 0.f;
    #pragma unroll
    for (int f = 0; f < 10; ++f) s += conv1_w[f * K_DIM + c];
    w_mean[c] = s * 0.1f;
  }
  if (blockIdx.x == 0 && threadIdx.x == 0){
    float s = 0.f;
    #pragma unroll
    for (int f = 0; f < 10; ++f) s += conv1_b[f];
    *b_mean = s * 0.1f;
  }
}

// K2: pooled[row] = x[row,:].w_mean + b_mean  AND  xbf[row,:] = bf16(x[row,:])
__global__ __launch_bounds__(256)
void pooled_kernel(const float* __restrict__ X, const float* __restrict__ w_mean,
                   const float* __restrict__ b_mean, float* __restrict__ pooled,
                   unsigned short* __restrict__ xbf)
{
  const int row = blockIdx.x;
  const int tid = threadIdx.x;
  const float* xr = X + (size_t)row * K_DIM;
  unsigned short* xb = xbf + (size_t)row * K_DIM;
  float s = 0.f;
  #pragma unroll 2
  for (int i = 0; i < 8; ++i){
    int idx = (tid + 256 * i) * 8;
    float4 a0 = *(const float4*)(xr + idx);
    float4 a1 = *(const float4*)(xr + idx + 4);
    float4 w0 = *(const float4*)(w_mean + idx);
    float4 w1 = *(const float4*)(w_mean + idx + 4);
    s += a0.x*w0.x + a0.y*w0.y + a0.z*w0.z + a0.w*w0.w
       + a1.x*w1.x + a1.y*w1.y + a1.z*w1.z + a1.w*w1.w;
    uint4 p;
    p.x = bfpack2(a0.x, a0.y); p.y = bfpack2(a0.z, a0.w);
    p.z = bfpack2(a1.x, a1.y); p.w = bfpack2(a1.z, a1.w);
    *(uint4*)(xb + idx) = p;
  }
  #pragma unroll
  for (int off = 32; off; off >>= 1) s += __shfl_down(s, off);
  __shared__ float red[4];
  if ((tid & 63) == 0) red[tid >> 6] = s;
  __syncthreads();
  if (tid == 0) pooled[row] = red[0] + red[1] + red[2] + red[3] + *b_mean;
}

// K3: gates
__global__ __launch_bounds__(512)
void gates_kernel(const float* __restrict__ pooled, const float* __restrict__ fw,
                  const float* __restrict__ fb, const float* __restrict__ aw,
                  float* __restrict__ gates)
{
  __shared__ float ps[512];
  int tid = threadIdx.x;
  ps[tid] = pooled[tid];
  __syncthreads();
  int b = tid >> 5, s = tid & 31;
  float z = fb[s];
  #pragma unroll
  for (int t = 0; t < 32; ++t) z += ps[b * 32 + t] * fw[s * 32 + t];
  float mx = z;
  #pragma unroll
  for (int off = 16; off; off >>= 1) mx = fmaxf(mx, __shfl_xor(mx, off));
  float e = expf(z - mx);
  float sum = e;
  #pragma unroll
  for (int off = 16; off; off >>= 1) sum += __shfl_xor(sum, off);
  float sm = e / sum;
  float relu = z > 0.f ? z : 0.f;
  float sig = 1.f / (1.f + expf(-z));
  gates[tid] = aw[0] * relu + aw[1] * sig + aw[2] * sm;
}

// K4 v15: R12 geometry + single-barrier counted-vmcnt + setprio (v14 fixed:
// no LDS pointer arrays -- inline offset arithmetic only).
// BM=256 x BN=160, BK=64, KSPLIT=8 -> grid 256 (1 block/CU).
// 8 waves 4m x 2n, wave tile 64x80 (acc[4][5]). kz=id&7 XCD-pinned.
// Ledger (4 gll A / 5 B-loads per thread): writeB waits rb (compiler vmcnt(4):
// drains B(t+1), keeps gll(t+1)); loadB(t+2) rides across the barrier; after
// compute: vmcnt(5) drains exactly gll(t+1); ONE s_barrier; stageA(t+2) into
// the A-buffer just freed. No fresh load is ever drained at a barrier.
__global__ __launch_bounds__(512, 2)
void gemm_kernel(const unsigned short* __restrict__ Abf, const float* __restrict__ W,
                 float* __restrict__ outp, int mode)
{
  __shared__ __align__(16) char smem[106496];  // A[2] 32KB each | B[2] 20KB each

  const int tid  = threadIdx.x;
  const int lane = tid & 63;
  const int wv   = tid >> 6;
  const int wm   = (wv >> 1) * 64;      // 4 m-waves
  const int wn   = (wv & 1) * 80;       // 2 n-waves

  const int id = blockIdx.x;
  const int kz = id & 7;
  const int r  = id >> 3;               // 0..31
  const int m0 = (r & 1) * BM;          // m fastest: W-strip sharers same XCD
  const int n0 = (r >> 1) * BN;
  const int kbase = kz * KCH;

  f32x4 acc[4][5] = {};

  // A gll: chunk u = j*512 + tid -> row = j*64 + (tid>>3), c8 = tid&7.
  const int arow0 = tid >> 3;
  const int ac8   = (tid & 7) ^ (arow0 & 7);
  const unsigned short* asrc = Abf + (size_t)(m0 + arow0) * K_DIM + ac8 * 8;
  const int adst = tid * 16;

  auto stageA = [&](int abuf, int k0){
    char* dst = smem + (abuf << 15);
    #pragma unroll
    for (int j = 0; j < 4; ++j){
      __builtin_amdgcn_global_load_lds(
        (const __attribute__((address_space(1))) void*)(asrc + (size_t)j * 64 * K_DIM + k0),
        (__attribute__((address_space(3))) void*)(dst + j * 8192 + adst),
        16, 0, 0);
    }
  };

  // B staging: 160 rows x 16 float4 = 2560 chunks; thread u = j*512+tid (j=0..4)
  const float* bsrcs[5];
  int boff[5];
  #pragma unroll
  for (int j = 0; j < 5; ++j){
    int u = j * 512 + tid;
    int brow = u >> 4;            // 0..159
    int bc4  = u & 15;
    bsrcs[j] = W + (size_t)(n0 + brow) * K_DIM + kbase + bc4 * 4;
    boff[j]  = brow * 128 + ((bc4 * 8) ^ ((brow & 7) << 4));
  }

  float4 rb[5];
  auto loadB = [&](int kt){
    #pragma unroll
    for (int j = 0; j < 5; ++j) rb[j] = *(const float4*)(bsrcs[j] + kt * BK);
  };
  auto writeB = [&](int bbuf){
    char* dst = smem + 65536 + bbuf * 20480;
    #pragma unroll
    for (int j = 0; j < 5; ++j){
      uint2 u;
      u.x = cpk2(rb[j].x, rb[j].y);
      u.y = cpk2(rb[j].z, rb[j].w);
      *(uint2*)(dst + boff[j]) = u;
    }
  };

  auto compute = [&](int abuf, int bbuf){
    const char* A_ = smem + (abuf << 15);
    const char* B_ = smem + 65536 + bbuf * 20480;
    #pragma unroll
    for (int kk = 0; kk < 2; ++kk){
      bf16x8 af[4], bfv[5];
      const int kbyte = kk * 64 + (lane >> 4) * 16;
      #pragma unroll
      for (int i = 0; i < 4; ++i){
        int row = wm + i * 16 + (lane & 15);
        af[i] = *(const bf16x8*)(A_ + row * 128 + (kbyte ^ ((row & 7) << 4)));
      }
      #pragma unroll
      for (int j = 0; j < 5; ++j){
        int rowb = wn + j * 16 + (lane & 15);
        bfv[j] = *(const bf16x8*)(B_ + rowb * 128 + (kbyte ^ ((rowb & 7) << 4)));
      }
      __builtin_amdgcn_s_setprio(1);
      #pragma unroll
      for (int i = 0; i < 4; ++i)
        #pragma unroll
        for (int j = 0; j < 5; ++j)
          acc[i][j] = __builtin_amdgcn_mfma_f32_16x16x32_bf16(af[i], bfv[j], acc[i][j], 0, 0, 0);
      __builtin_amdgcn_s_setprio(0);
    }
  };

  // ---- prologue ----
  loadB(0);                                   // 5 vm (B0)
  stageA(0, kbase);                           // +4 (gll0)
  writeB(0);                                  // rb dep -> compiler vmcnt(4): B0 done
  loadB(1);                                   // +5 (B1)
  stageA(1, kbase + BK);                      // +4 (gll1)
  asm volatile("s_waitcnt vmcnt(9) lgkmcnt(0)" ::: "memory");  // drain gll0 + B0 ds_writes
  __builtin_amdgcn_s_barrier();               // tile0 published; B1+gll1 in flight
  __builtin_amdgcn_sched_barrier(0);

  // ---- main loop: ONE barrier per K-step ----
  for (int t = 0; t < NT; ++t){
    writeB((t + 1) & 1);                      // uses B(t+1); keeps gll(t+1) flying
    loadB(t + 2 < NT ? t + 2 : NT - 1);       // 5 vm ride across the barrier
    compute(t & 1, t & 1);                    // covers gll(t+1) latency
    asm volatile("s_waitcnt vmcnt(5) lgkmcnt(0)" ::: "memory");  // drain gll(t+1) only
    __builtin_amdgcn_s_barrier();             // publish tile t+1
    __builtin_amdgcn_sched_barrier(0);
    if (t + 2 < NT)
      stageA(t & 1, kbase + (t + 2) * BK);    // gll A(t+2) into freed buffer
  }

  // ---- epilogue ----
  if (mode == 0){
    float* P = outp + (size_t)kz * M_DIM * N_DIM;
    #pragma unroll
    for (int i = 0; i < 4; ++i){
      int rbase = m0 + wm + i * 16 + (lane >> 4) * 4;
      #pragma unroll
      for (int j = 0; j < 5; ++j){
        int col = n0 + wn + j * 16 + (lane & 15);
        #pragma unroll
        for (int r2 = 0; r2 < 4; ++r2)
          P[(size_t)(rbase + r2) * N_DIM + col] = acc[i][j][r2];
      }
    }
  } else {
    #pragma unroll
    for (int i = 0; i < 4; ++i){
      int rbase = m0 + wm + i * 16 + (lane >> 4) * 4;
      #pragma unroll
      for (int j = 0; j < 5; ++j){
        int col = n0 + wn + j * 16 + (lane & 15);
        #pragma unroll
        for (int r2 = 0; r2 < 4; ++r2)
          atomicAdd(&outp[(size_t)(rbase + r2) * N_DIM + col], acc[i][j][r2]);
      }
    }
  }
}

// K5a: out[m,n] = gates[m] * (sum_z partial[z,m,n] + bias[n])
__global__ __launch_bounds__(256)
void reduce_kernel(const float* __restrict__ part, const float* __restrict__ gates,
                   const float* __restrict__ bias, float* __restrict__ out, int ksplit)
{
  int i4 = blockIdx.x * 256 + threadIdx.x;
  if (i4 >= M_DIM * N_DIM / 4) return;
  size_t off = (size_t)i4 * 4;
  int m = (int)(off / N_DIM);
  int n = (int)(off % N_DIM);
  float sx = 0.f, sy = 0.f, sz = 0.f, sw = 0.f;
  for (int z = 0; z < ksplit; ++z){
    float4 p = *(const float4*)(part + (size_t)z * M_DIM * N_DIM + off);
    sx += p.x; sy += p.y; sz += p.z; sw += p.w;
  }
  float4 bv = *(const float4*)(bias + n);
  float g = gates[m];
  float4 o;
  o.x = g * (sx + bv.x); o.y = g * (sy + bv.y);
  o.z = g * (sz + bv.z); o.w = g * (sw + bv.w);
  *(float4*)(out + off) = o;
}

// K5b: finalize after atomic accumulation
__global__ __launch_bounds__(256)
void finalize_kernel(float* __restrict__ out, const float* __restrict__ gates,
                     const float* __restrict__ bias)
{
  int i4 = blockIdx.x * 256 + threadIdx.x;
  if (i4 >= M_DIM * N_DIM / 4) return;
  size_t off = (size_t)i4 * 4;
  int m = (int)(off / N_DIM);
  int n = (int)(off % N_DIM);
  float4 o = *(const float4*)(out + off);
  float4 bv = *(const float4*)(bias + n);
  float g = gates[m];
  o.x = g * (o.x + bv.x); o.y = g * (o.y + bv.y);
  o.z = g * (o.z + bv.z); o.w = g * (o.w + bv.w);
  *(float4*)(out + off) = o;
}

extern "C" void kernel_launch(void* const* d_in, const int* in_sizes, int n_in,
                              void* d_out, int out_size, void* d_ws, size_t ws_size,
                              hipStream_t stream)
{
  const float* input   = (const float*)d_in[0];
  const float* aw      = (const float*)d_in[2];
  const float* conv1_w = (const float*)d_in[3];
  const float* conv1_b = (const float*)d_in[4];
  const float* G3_w    = (const float*)d_in[5];
  const float* G3_b    = (const float*)d_in[6];
  const float* ffnn1_w = (const float*)d_in[7];
  const float* ffnn1_b = (const float*)d_in[8];
  float* out = (float*)d_out;

  float* wsf    = (float*)d_ws;
  float* w_mean = wsf;               // 16384 f
  float* pooled = wsf + 16384;       // 512 f
  float* gates  = wsf + 16896;       // 512 f
  float* b_mean = wsf + 17408;       // 64 f pad
  unsigned short* xbf = (unsigned short*)(wsf + 17472);        // 16 MB
  float* partial = wsf + 17472 + (size_t)M_DIM * K_DIM / 2;    // 8 * 512*2560 f

  const size_t need_det = ((size_t)17472 + (size_t)M_DIM * K_DIM / 2
                           + (size_t)KSPLIT * M_DIM * N_DIM) * 4;   // ~58.8MB

  prep_kernel<<<64, 256, 0, stream>>>(conv1_w, conv1_b, w_mean, b_mean);
  pooled_kernel<<<512, 256, 0, stream>>>(input, w_mean, b_mean, pooled, xbf);
  gates_kernel<<<1, 512, 0, stream>>>(pooled, ffnn1_w, ffnn1_b, aw, gates);

  const int n4 = M_DIM * N_DIM / 4;
  const int grid = (M_DIM / BM) * (N_DIM / BN) * KSPLIT;   // 2*16*8 = 256
  if (ws_size >= need_det){
    gemm_kernel<<<grid, 512, 0, stream>>>(xbf, G3_w, partial, 0);
    reduce_kernel<<<(n4 + 255) / 256, 256, 0, stream>>>(partial, gates, G3_b, out, KSPLIT);
  } else {
    (void)hipMemsetAsync(d_out, 0, (size_t)out_size * sizeof(float), stream);
    gemm_kernel<<<grid, 512, 0, stream>>>(xbf, G3_w, out, 2);
    finalize_kernel<<<(n4 + 255) / 256, 256, 0, stream>>>(out, gates, G3_b);
  }
}

// Round 17
// 83.672 us; speedup vs baseline: 1.2260x; 1.0532x over previous
//
#include <hip/hip_runtime.h>
#include <hip/hip_bf16.h>

#define K_DIM 16384
#define M_DIM 512
#define N_DIM 2560
#define BM 256
#define BN 160
#define BK 64
#define KSPLIT 8
#define KCH (K_DIM / KSPLIT)   // 2048
#define NT (KCH / BK)          // 32

typedef float f32x4 __attribute__((ext_vector_type(4)));
typedef __bf16 bf16x8 __attribute__((ext_vector_type(8)));

__device__ __forceinline__ unsigned short f2bf(float f){
  union { float f; unsigned u; } v; v.f = f;
  unsigned r = v.u + 0x7FFFu + ((v.u >> 16) & 1u);
  return (unsigned short)(r >> 16);
}
__device__ __forceinline__ unsigned bfpack2(float lo, float hi){
  return (unsigned)f2bf(lo) | ((unsigned)f2bf(hi) << 16);
}
// compiler-cvt pack (emits v_cvt_pk_bf16_f32)
__device__ __forceinline__ unsigned cpk2(float lo, float hi){
  __bf16 a = (__bf16)lo, b = (__bf16)hi;
  unsigned short ua = __builtin_bit_cast(unsigned short, a);
  unsigned short ub = __builtin_bit_cast(unsigned short, b);
  return (unsigned)ua | ((unsigned)ub << 16);
}
__device__ __forceinline__ unsigned short cbf(float f){
  __bf16 a = (__bf16)f;
  return __builtin_bit_cast(unsigned short, a);
}

// K1: w_mean[c] = mean_f conv1_w[f][c]; b_mean = mean(conv1_b)
__global__ __launch_bounds__(256)
void prep_kernel(const float* __restrict__ conv1_w, const float* __restrict__ conv1_b,
                 float* __restrict__ w_mean, float* __restrict__ b_mean)
{
  int c = blockIdx.x * 256 + threadIdx.x;
  if (c < K_DIM){
    float s = 0.f;
    #pragma unroll
    for (int f = 0; f < 10; ++f) s += conv1_w[f * K_DIM + c];
    w_mean[c] = s * 0.1f;
  }
  if (blockIdx.x == 0 && threadIdx.x == 0){
    float s = 0.f;
    #pragma unroll
    for (int f = 0; f < 10; ++f) s += conv1_b[f];
    *b_mean = s * 0.1f;
  }
}

// K2: pooled[row] = x[row,:].w_mean + b_mean  AND  xbf[row,:] = bf16(x[row,:])
__global__ __launch_bounds__(256)
void pooled_kernel(const float* __restrict__ X, const float* __restrict__ w_mean,
                   const float* __restrict__ b_mean, float* __restrict__ pooled,
                   unsigned short* __restrict__ xbf)
{
  const int row = blockIdx.x;
  const int tid = threadIdx.x;
  const float* xr = X + (size_t)row * K_DIM;
  unsigned short* xb = xbf + (size_t)row * K_DIM;
  float s = 0.f;
  #pragma unroll 2
  for (int i = 0; i < 8; ++i){
    int idx = (tid + 256 * i) * 8;
    float4 a0 = *(const float4*)(xr + idx);
    float4 a1 = *(const float4*)(xr + idx + 4);
    float4 w0 = *(const float4*)(w_mean + idx);
    float4 w1 = *(const float4*)(w_mean + idx + 4);
    s += a0.x*w0.x + a0.y*w0.y + a0.z*w0.z + a0.w*w0.w
       + a1.x*w1.x + a1.y*w1.y + a1.z*w1.z + a1.w*w1.w;
    uint4 p;
    p.x = bfpack2(a0.x, a0.y); p.y = bfpack2(a0.z, a0.w);
    p.z = bfpack2(a1.x, a1.y); p.w = bfpack2(a1.z, a1.w);
    *(uint4*)(xb + idx) = p;
  }
  #pragma unroll
  for (int off = 32; off; off >>= 1) s += __shfl_down(s, off);
  __shared__ float red[4];
  if ((tid & 63) == 0) red[tid >> 6] = s;
  __syncthreads();
  if (tid == 0) pooled[row] = red[0] + red[1] + red[2] + red[3] + *b_mean;
}

// K3: gates
__global__ __launch_bounds__(512)
void gates_kernel(const float* __restrict__ pooled, const float* __restrict__ fw,
                  const float* __restrict__ fb, const float* __restrict__ aw,
                  float* __restrict__ gates)
{
  __shared__ float ps[512];
  int tid = threadIdx.x;
  ps[tid] = pooled[tid];
  __syncthreads();
  int b = tid >> 5, s = tid & 31;
  float z = fb[s];
  #pragma unroll
  for (int t = 0; t < 32; ++t) z += ps[b * 32 + t] * fw[s * 32 + t];
  float mx = z;
  #pragma unroll
  for (int off = 16; off; off >>= 1) mx = fmaxf(mx, __shfl_xor(mx, off));
  float e = expf(z - mx);
  float sum = e;
  #pragma unroll
  for (int off = 16; off; off >>= 1) sum += __shfl_xor(sum, off);
  float sm = e / sum;
  float relu = z > 0.f ? z : 0.f;
  float sig = 1.f / (1.f + expf(-z));
  gates[tid] = aw[0] * relu + aw[1] * sig + aw[2] * sm;
}

// K4 v16: proven v15 single-barrier counted-vmcnt loop, unchanged, except the
// mode-0 epilogue now writes BF16 partials (halves split-K traffic; error
// <=0.004 absolute vs 0.124 threshold).
__global__ __launch_bounds__(512, 2)
void gemm_kernel(const unsigned short* __restrict__ Abf, const float* __restrict__ W,
                 void* __restrict__ outp, int mode)
{
  __shared__ __align__(16) char smem[106496];  // A[2] 32KB each | B[2] 20KB each

  const int tid  = threadIdx.x;
  const int lane = tid & 63;
  const int wv   = tid >> 6;
  const int wm   = (wv >> 1) * 64;      // 4 m-waves
  const int wn   = (wv & 1) * 80;       // 2 n-waves

  const int id = blockIdx.x;
  const int kz = id & 7;
  const int r  = id >> 3;               // 0..31
  const int m0 = (r & 1) * BM;          // m fastest: W-strip sharers same XCD
  const int n0 = (r >> 1) * BN;
  const int kbase = kz * KCH;

  f32x4 acc[4][5] = {};

  // A gll: chunk u = j*512 + tid -> row = j*64 + (tid>>3), c8 = tid&7.
  const int arow0 = tid >> 3;
  const int ac8   = (tid & 7) ^ (arow0 & 7);
  const unsigned short* asrc = Abf + (size_t)(m0 + arow0) * K_DIM + ac8 * 8;
  const int adst = tid * 16;

  auto stageA = [&](int abuf, int k0){
    char* dst = smem + (abuf << 15);
    #pragma unroll
    for (int j = 0; j < 4; ++j){
      __builtin_amdgcn_global_load_lds(
        (const __attribute__((address_space(1))) void*)(asrc + (size_t)j * 64 * K_DIM + k0),
        (__attribute__((address_space(3))) void*)(dst + j * 8192 + adst),
        16, 0, 0);
    }
  };

  // B staging: 160 rows x 16 float4 = 2560 chunks; thread u = j*512+tid (j=0..4)
  const float* bsrcs[5];
  int boff[5];
  #pragma unroll
  for (int j = 0; j < 5; ++j){
    int u = j * 512 + tid;
    int brow = u >> 4;            // 0..159
    int bc4  = u & 15;
    bsrcs[j] = W + (size_t)(n0 + brow) * K_DIM + kbase + bc4 * 4;
    boff[j]  = brow * 128 + ((bc4 * 8) ^ ((brow & 7) << 4));
  }

  float4 rb[5];
  auto loadB = [&](int kt){
    #pragma unroll
    for (int j = 0; j < 5; ++j) rb[j] = *(const float4*)(bsrcs[j] + kt * BK);
  };
  auto writeB = [&](int bbuf){
    char* dst = smem + 65536 + bbuf * 20480;
    #pragma unroll
    for (int j = 0; j < 5; ++j){
      uint2 u;
      u.x = cpk2(rb[j].x, rb[j].y);
      u.y = cpk2(rb[j].z, rb[j].w);
      *(uint2*)(dst + boff[j]) = u;
    }
  };

  auto compute = [&](int abuf, int bbuf){
    const char* A_ = smem + (abuf << 15);
    const char* B_ = smem + 65536 + bbuf * 20480;
    #pragma unroll
    for (int kk = 0; kk < 2; ++kk){
      bf16x8 af[4], bfv[5];
      const int kbyte = kk * 64 + (lane >> 4) * 16;
      #pragma unroll
      for (int i = 0; i < 4; ++i){
        int row = wm + i * 16 + (lane & 15);
        af[i] = *(const bf16x8*)(A_ + row * 128 + (kbyte ^ ((row & 7) << 4)));
      }
      #pragma unroll
      for (int j = 0; j < 5; ++j){
        int rowb = wn + j * 16 + (lane & 15);
        bfv[j] = *(const bf16x8*)(B_ + rowb * 128 + (kbyte ^ ((rowb & 7) << 4)));
      }
      __builtin_amdgcn_s_setprio(1);
      #pragma unroll
      for (int i = 0; i < 4; ++i)
        #pragma unroll
        for (int j = 0; j < 5; ++j)
          acc[i][j] = __builtin_amdgcn_mfma_f32_16x16x32_bf16(af[i], bfv[j], acc[i][j], 0, 0, 0);
      __builtin_amdgcn_s_setprio(0);
    }
  };

  // ---- prologue ----
  loadB(0);                                   // 5 vm (B0)
  stageA(0, kbase);                           // +4 (gll0)
  writeB(0);                                  // rb dep -> compiler vmcnt(4): B0 done
  loadB(1);                                   // +5 (B1)
  stageA(1, kbase + BK);                      // +4 (gll1)
  asm volatile("s_waitcnt vmcnt(9) lgkmcnt(0)" ::: "memory");  // drain gll0 + B0 ds_writes
  __builtin_amdgcn_s_barrier();               // tile0 published; B1+gll1 in flight
  __builtin_amdgcn_sched_barrier(0);

  // ---- main loop: ONE barrier per K-step ----
  for (int t = 0; t < NT; ++t){
    writeB((t + 1) & 1);                      // uses B(t+1); keeps gll(t+1) flying
    loadB(t + 2 < NT ? t + 2 : NT - 1);       // 5 vm ride across the barrier
    compute(t & 1, t & 1);                    // covers gll(t+1) latency
    asm volatile("s_waitcnt vmcnt(5) lgkmcnt(0)" ::: "memory");  // drain gll(t+1) only
    __builtin_amdgcn_s_barrier();             // publish tile t+1
    __builtin_amdgcn_sched_barrier(0);
    if (t + 2 < NT)
      stageA(t & 1, kbase + (t + 2) * BK);    // gll A(t+2) into freed buffer
  }

  // ---- epilogue ----
  if (mode == 0){
    unsigned short* P = (unsigned short*)outp + (size_t)kz * M_DIM * N_DIM;
    #pragma unroll
    for (int i = 0; i < 4; ++i){
      int rbase = m0 + wm + i * 16 + (lane >> 4) * 4;
      #pragma unroll
      for (int j = 0; j < 5; ++j){
        int col = n0 + wn + j * 16 + (lane & 15);
        #pragma unroll
        for (int r2 = 0; r2 < 4; ++r2)
          P[(size_t)(rbase + r2) * N_DIM + col] = cbf(acc[i][j][r2]);
      }
    }
  } else {
    float* P = (float*)outp;
    #pragma unroll
    for (int i = 0; i < 4; ++i){
      int rbase = m0 + wm + i * 16 + (lane >> 4) * 4;
      #pragma unroll
      for (int j = 0; j < 5; ++j){
        int col = n0 + wn + j * 16 + (lane & 15);
        #pragma unroll
        for (int r2 = 0; r2 < 4; ++r2)
          atomicAdd(&P[(size_t)(rbase + r2) * N_DIM + col], acc[i][j][r2]);
      }
    }
  }
}

// K5a: out[m,n] = gates[m] * (sum_z bf16_part[z,m,n] + bias[n]); 8 elems/thread
__global__ __launch_bounds__(256)
void reduce_kernel(const unsigned short* __restrict__ part, const float* __restrict__ gates,
                   const float* __restrict__ bias, float* __restrict__ out, int ksplit)
{
  int i8 = blockIdx.x * 256 + threadIdx.x;
  if (i8 >= M_DIM * N_DIM / 8) return;
  size_t off = (size_t)i8 * 8;
  int m = (int)(off / N_DIM);
  int n = (int)(off % N_DIM);
  float s[8] = {};
  for (int z = 0; z < ksplit; ++z){
    uint4 p = *(const uint4*)(part + (size_t)z * M_DIM * N_DIM + off);
    unsigned w[4] = { p.x, p.y, p.z, p.w };
    #pragma unroll
    for (int q = 0; q < 4; ++q){
      union { unsigned u; float f; } lo, hi;
      lo.u = (w[q] & 0xFFFFu) << 16;
      hi.u = (w[q] & 0xFFFF0000u);
      s[2*q]   += lo.f;
      s[2*q+1] += hi.f;
    }
  }
  float g = gates[m];
  float4 b0 = *(const float4*)(bias + n);
  float4 b1 = *(const float4*)(bias + n + 4);
  float4 o0, o1;
  o0.x = g * (s[0] + b0.x); o0.y = g * (s[1] + b0.y);
  o0.z = g * (s[2] + b0.z); o0.w = g * (s[3] + b0.w);
  o1.x = g * (s[4] + b1.x); o1.y = g * (s[5] + b1.y);
  o1.z = g * (s[6] + b1.z); o1.w = g * (s[7] + b1.w);
  *(float4*)(out + off) = o0;
  *(float4*)(out + off + 4) = o1;
}

// K5b: finalize after atomic accumulation
__global__ __launch_bounds__(256)
void finalize_kernel(float* __restrict__ out, const float* __restrict__ gates,
                     const float* __restrict__ bias)
{
  int i4 = blockIdx.x * 256 + threadIdx.x;
  if (i4 >= M_DIM * N_DIM / 4) return;
  size_t off = (size_t)i4 * 4;
  int m = (int)(off / N_DIM);
  int n = (int)(off % N_DIM);
  float4 o = *(const float4*)(out + off);
  float4 bv = *(const float4*)(bias + n);
  float g = gates[m];
  o.x = g * (o.x + bv.x); o.y = g * (o.y + bv.y);
  o.z = g * (o.z + bv.z); o.w = g * (o.w + bv.w);
  *(float4*)(out + off) = o;
}

extern "C" void kernel_launch(void* const* d_in, const int* in_sizes, int n_in,
                              void* d_out, int out_size, void* d_ws, size_t ws_size,
                              hipStream_t stream)
{
  const float* input   = (const float*)d_in[0];
  const float* aw      = (const float*)d_in[2];
  const float* conv1_w = (const float*)d_in[3];
  const float* conv1_b = (const float*)d_in[4];
  const float* G3_w    = (const float*)d_in[5];
  const float* G3_b    = (const float*)d_in[6];
  const float* ffnn1_w = (const float*)d_in[7];
  const float* ffnn1_b = (const float*)d_in[8];
  float* out = (float*)d_out;

  float* wsf    = (float*)d_ws;
  float* w_mean = wsf;               // 16384 f
  float* pooled = wsf + 16384;       // 512 f
  float* gates  = wsf + 16896;       // 512 f
  float* b_mean = wsf + 17408;       // 64 f pad
  unsigned short* xbf = (unsigned short*)(wsf + 17472);        // 16 MB
  unsigned short* partial = xbf + (size_t)M_DIM * K_DIM;       // 8*512*2560 bf16 = 21 MB

  const size_t need_det = (size_t)17472 * 4 + (size_t)M_DIM * K_DIM * 2
                          + (size_t)KSPLIT * M_DIM * N_DIM * 2;   // ~38 MB

  prep_kernel<<<64, 256, 0, stream>>>(conv1_w, conv1_b, w_mean, b_mean);
  pooled_kernel<<<512, 256, 0, stream>>>(input, w_mean, b_mean, pooled, xbf);
  gates_kernel<<<1, 512, 0, stream>>>(pooled, ffnn1_w, ffnn1_b, aw, gates);

  const int grid = (M_DIM / BM) * (N_DIM / BN) * KSPLIT;   // 2*16*8 = 256
  if (ws_size >= need_det){
    gemm_kernel<<<grid, 512, 0, stream>>>(xbf, G3_w, partial, 0);
    const int n8 = M_DIM * N_DIM / 8;
    reduce_kernel<<<(n8 + 255) / 256, 256, 0, stream>>>(partial, gates, G3_b, out, KSPLIT);
  } else {
    (void)hipMemsetAsync(d_out, 0, (size_t)out_size * sizeof(float), stream);
    gemm_kernel<<<grid, 512, 0, stream>>>(xbf, G3_w, d_out, 2);
    const int n4 = M_DIM * N_DIM / 4;
    finalize_kernel<<<(n4 + 255) / 256, 256, 0, stream>>>(out, gates, G3_b);
  }
}